// Round 1
// baseline (1326.795 us; speedup 1.0000x reference)
//
#include <hip/hip_runtime.h>
#include <math.h>

#define N_NODES 4096
#define T_LEN 1000
#define TCH 16
#define AHD 32
#define F3D 48
#define GCD 32
#define NHEADS 4
#define NPG 64      // nodes per graph
#define NGRAPH 64
#define BN_EPS 1e-5f

__device__ __forceinline__ float gelu_exact(float v){
    return 0.5f*v*(1.0f+erff(v*0.70710678118654752f));
}

// ---------------------------------------------------------------------------
// Branch: conv1d(k) + BN + GELU + attention pooling over T. One block per node.
// ---------------------------------------------------------------------------
template<int K>
__global__ __launch_bounds__(256)
void branch_kernel(const float* __restrict__ x,
                   const float* __restrict__ conv_w, const float* __restrict__ conv_b,
                   const float* __restrict__ bn_g, const float* __restrict__ bn_b,
                   const float* __restrict__ bn_m, const float* __restrict__ bn_v,
                   const float* __restrict__ aw1, const float* __restrict__ ab1,
                   const float* __restrict__ aw2, const float* __restrict__ ab2,
                   float* __restrict__ xf, int col0)
{
    __shared__ float xs[T_LEN+6];      // 3-elem zero guard both sides
    __shared__ float cws[TCH*K];
    __shared__ float shiftc[TCH];
    __shared__ float scl[TCH];
    __shared__ float w1s[AHD*TCH];
    __shared__ float b1s[AHD];
    __shared__ float w2s[AHD];
    __shared__ float redm[4];
    __shared__ float reds[4];
    __shared__ float fred[4][TCH];

    const int tid = threadIdx.x;
    const int node = blockIdx.x;
    const float* xrow = x + (size_t)node*T_LEN;

    for (int i=tid;i<T_LEN+6;i+=256){
        int q = i-3;
        xs[i] = (q>=0 && q<T_LEN) ? xrow[q] : 0.f;
    }
    if (tid<TCH){
        float s = bn_g[tid]*rsqrtf(bn_v[tid]+BN_EPS);
        scl[tid]=s;
        shiftc[tid] = (conv_b[tid]-bn_m[tid])*s + bn_b[tid];
    }
    if (tid<AHD){ b1s[tid]=ab1[tid]; w2s[tid]=aw2[tid]; }
    __syncthreads();
    for (int i=tid;i<TCH*K;i+=256){
        int c=i/K;
        cws[i]=conv_w[i]*scl[c];       // fold BN scale into conv weights
    }
    for (int i=tid;i<AHD*TCH;i+=256) w1s[i]=aw1[i];
    const float b2v = ab2[0];
    __syncthreads();

    float o[4][TCH];
    float sv[4];
    #pragma unroll
    for (int ii=0;ii<4;ii++){
        int p = tid + ii*256;
        bool valid = (p < T_LEN);
        float s = -INFINITY;
        if (valid){
            const float* xp = &xs[p + 3 - K/2];
            #pragma unroll
            for (int c=0;c<TCH;c++){
                float acc = shiftc[c];
                #pragma unroll
                for (int j=0;j<K;j++) acc += cws[c*K+j]*xp[j];
                o[ii][c] = gelu_exact(acc);
            }
            float ssum = b2v;
            #pragma unroll
            for (int a=0;a<AHD;a++){
                float hh = b1s[a];
                #pragma unroll
                for (int c=0;c<TCH;c++) hh += w1s[a*TCH+c]*o[ii][c];
                ssum += w2s[a]*tanhf(hh);
            }
            s = ssum;
        } else {
            #pragma unroll
            for (int c=0;c<TCH;c++) o[ii][c]=0.f;
        }
        sv[ii]=s;
    }

    // block-wide softmax over the 1000 positions
    float m = fmaxf(fmaxf(sv[0],sv[1]),fmaxf(sv[2],sv[3]));
    #pragma unroll
    for (int off=32;off;off>>=1) m = fmaxf(m, __shfl_xor(m,off));
    int wave = tid>>6, lane = tid&63;
    if (lane==0) redm[wave]=m;
    __syncthreads();
    float bm = fmaxf(fmaxf(redm[0],redm[1]),fmaxf(redm[2],redm[3]));

    float e[4]; float ls=0.f;
    #pragma unroll
    for (int ii=0;ii<4;ii++){ e[ii]=expf(sv[ii]-bm); ls+=e[ii]; }
    #pragma unroll
    for (int off=32;off;off>>=1) ls += __shfl_xor(ls,off);
    if (lane==0) reds[wave]=ls;
    __syncthreads();
    float S = reds[0]+reds[1]+reds[2]+reds[3];
    float invS = 1.0f/S;

    #pragma unroll
    for (int c=0;c<TCH;c++){
        float f = o[0][c]*e[0]+o[1][c]*e[1]+o[2][c]*e[2]+o[3][c]*e[3];
        #pragma unroll
        for (int off=32;off;off>>=1) f += __shfl_xor(f,off);
        if (lane==0) fred[wave][c]=f;
    }
    __syncthreads();
    if (tid<TCH){
        float tot = (fred[0][tid]+fred[1][tid]+fred[2][tid]+fred[3][tid])*invS;
        xf[(size_t)node*F3D + col0 + tid] = tot;
    }
}

// ---------------------------------------------------------------------------
// SE block
// ---------------------------------------------------------------------------
__global__ __launch_bounds__(256)
void colsum_kernel(const float* __restrict__ xf, float* __restrict__ colmean){
    int col = blockIdx.x;
    int tid = threadIdx.x;
    float s=0.f;
    for (int i=tid;i<N_NODES;i+=256) s += xf[(size_t)i*F3D+col];
    #pragma unroll
    for (int off=32;off;off>>=1) s += __shfl_xor(s,off);
    __shared__ float red[4];
    if ((tid&63)==0) red[tid>>6]=s;
    __syncthreads();
    if (tid==0) colmean[col] = (red[0]+red[1]+red[2]+red[3])*(1.0f/(float)N_NODES);
}

__global__ __launch_bounds__(64)
void gate_kernel(const float* __restrict__ colmean,
                 const float* __restrict__ se_w1, const float* __restrict__ se_b1,
                 const float* __restrict__ se_w2, const float* __restrict__ se_b2,
                 float* __restrict__ gate){
    __shared__ float sq[F3D];
    __shared__ float g1[12];
    int tid=threadIdx.x;
    if (tid<F3D) sq[tid]=colmean[tid];
    __syncthreads();
    if (tid<12){
        float v=se_b1[tid];
        for (int j=0;j<F3D;j++) v += se_w1[tid*F3D+j]*sq[j];
        g1[tid]=gelu_exact(v);
    }
    __syncthreads();
    if (tid<F3D){
        float v=se_b2[tid];
        for (int m2=0;m2<12;m2++) v += se_w2[tid*12+m2]*g1[m2];
        gate[tid] = 1.0f/(1.0f+expf(-v));
    }
}

__global__ __launch_bounds__(256)
void scale_kernel(float* __restrict__ xf, const float* __restrict__ gate){
    int idx = blockIdx.x*256+threadIdx.x;
    if (idx < N_NODES*F3D) xf[idx] *= gate[idx%F3D];
}

// ---------------------------------------------------------------------------
// GAT: node transform h = x @ W.T  plus attention logits al_s/al_d
// ---------------------------------------------------------------------------
template<int INF>
__global__ __launch_bounds__(128)
void gat_h_kernel(const float* __restrict__ xin_g, const float* __restrict__ W,
                  const float* __restrict__ a_src, const float* __restrict__ a_dst,
                  float* __restrict__ hbuf, float* __restrict__ als, float* __restrict__ ald){
    __shared__ float xin[INF];
    __shared__ float hs[128];
    int node=blockIdx.x, tid=threadIdx.x;
    if (tid<INF) xin[tid]=xin_g[(size_t)node*INF+tid];
    __syncthreads();
    float acc=0.f;
    const float* wr = W + (size_t)tid*INF;
    #pragma unroll
    for (int j=0;j<INF;j++) acc += wr[j]*xin[j];
    hs[tid]=acc;
    hbuf[(size_t)node*128+tid]=acc;
    __syncthreads();
    if (tid<8){
        int head=tid&3;
        const float* av = (tid<4)? a_src : a_dst;
        float s=0.f;
        for (int c=0;c<GCD;c++) s += hs[head*GCD+c]*av[head*GCD+c];
        if (tid<4) als[(size_t)node*4+head]=s;
        else       ald[(size_t)node*4+head]=s;
    }
}

// edge scatter: exp(leaky(e)) accumulated into numerator/denominator per dst
__global__ __launch_bounds__(256)
void edge_kernel(const int* __restrict__ ei, int epg,
                 const float* __restrict__ als, const float* __restrict__ ald,
                 const float* __restrict__ hbuf,
                 float* __restrict__ num, float* __restrict__ denom){
    int e = blockIdx.x*256+threadIdx.x;
    int be = NGRAPH*epg;
    int total = be + N_NODES;
    if (e>=total) return;
    int src,dst;
    if (e < be){ int b=e/epg, j=e-b*epg; src = ei[j]+b*NPG; dst = ei[epg+j]+b*NPG; }
    else { src=dst=e-be; }
    #pragma unroll
    for (int h=0;h<NHEADS;h++){
        float ev = als[(size_t)src*4+h]+ald[(size_t)dst*4+h];
        ev = ev>0.f? ev : 0.2f*ev;          // leaky_relu(0.2)
        float ex = expf(ev);                 // max-sub is mathematically redundant
        atomicAdd(&denom[(size_t)dst*4+h], ex);
        const float* hsrc = &hbuf[(size_t)src*128 + h*GCD];
        float* np = &num[(size_t)dst*128 + h*GCD];
        #pragma unroll
        for (int c=0;c<GCD;c++) atomicAdd(&np[c], hsrc[c]*ex);
    }
}

__global__ __launch_bounds__(64)
void final1_kernel(const float* __restrict__ num, const float* __restrict__ denom,
                   const float* __restrict__ bias,
                   const float* __restrict__ bn_g, const float* __restrict__ bn_b,
                   const float* __restrict__ bn_m, const float* __restrict__ bn_v,
                   const float* __restrict__ xf, const float* __restrict__ skip_w,
                   const float* __restrict__ skip_b,
                   float* __restrict__ h1){
    int node = blockIdx.x*2 + (threadIdx.x>>5);
    int c = threadIdx.x&31;
    float acc=0.f;
    #pragma unroll
    for (int h=0;h<NHEADS;h++) acc += num[(size_t)node*128+h*GCD+c]/denom[(size_t)node*4+h];
    acc = acc*0.25f + bias[c];
    acc = (acc-bn_m[c])*rsqrtf(bn_v[c]+BN_EPS)*bn_g[c]+bn_b[c];
    float sk = skip_b[c];
    const float* xr = xf+(size_t)node*F3D;
    #pragma unroll
    for (int j=0;j<F3D;j++) sk += xr[j]*skip_w[c*F3D+j];
    h1[(size_t)node*GCD+c]=gelu_exact(acc+sk);
}

__global__ __launch_bounds__(64)
void final2_kernel(const float* __restrict__ num, const float* __restrict__ denom,
                   const float* __restrict__ bias,
                   const float* __restrict__ bn_g, const float* __restrict__ bn_b,
                   const float* __restrict__ bn_m, const float* __restrict__ bn_v,
                   const float* __restrict__ h1, float* __restrict__ h2){
    int node = blockIdx.x*2 + (threadIdx.x>>5);
    int c = threadIdx.x&31;
    float acc=0.f;
    #pragma unroll
    for (int h=0;h<NHEADS;h++) acc += num[(size_t)node*128+h*GCD+c]/denom[(size_t)node*4+h];
    acc = acc*0.25f + bias[c];
    acc = (acc-bn_m[c])*rsqrtf(bn_v[c]+BN_EPS)*bn_g[c]+bn_b[c];
    float v = acc + h1[(size_t)node*GCD+c];
    h2[(size_t)node*GCD+c]=gelu_exact(v);
}

__global__ __launch_bounds__(64)
void pool_fc_kernel(const float* __restrict__ h2, const float* __restrict__ fc_w,
                    const float* __restrict__ fc_b, float* __restrict__ out){
    int g = blockIdx.x;
    int tid = threadIdx.x;
    __shared__ float part[2][GCD];
    __shared__ float pool[GCD];
    int c = tid&31, hf = tid>>5;
    float acc=0.f;
    for (int i=hf*32;i<hf*32+32;i++) acc += h2[((size_t)(g*NPG+i))*GCD+c];
    part[hf][c]=acc;
    __syncthreads();
    if (tid<GCD) pool[tid]=(part[0][tid]+part[1][tid])*(1.0f/(float)NPG);
    __syncthreads();
    if (tid<2){
        float o=fc_b[tid];
        for (int cc=0;cc<GCD;cc++) o += pool[cc]*fc_w[tid*GCD+cc];
        out[g*2+tid]=o;
    }
}

// ---------------------------------------------------------------------------
extern "C" void kernel_launch(void* const* d_in, const int* in_sizes, int n_in,
                              void* d_out, int out_size, void* d_ws, size_t ws_size,
                              hipStream_t stream){
    const float* x = (const float*)d_in[0];
    const int* ei = (const int*)d_in[1];
    int epg = in_sizes[1]/2;               // edges per graph (512)

    float* ws = (float*)d_ws;
    float* xf      = ws;                                   // [4096,48]
    float* colmean = xf + (size_t)N_NODES*F3D;             // [48]
    float* gate    = colmean + F3D;                        // [48]
    float* hbuf    = gate + F3D;                           // [4096,128]
    float* als     = hbuf + (size_t)N_NODES*128;           // [4096,4]
    float* ald     = als + (size_t)N_NODES*4;              // [4096,4]
    float* num     = ald + (size_t)N_NODES*4;              // [4096,128]
    float* denom   = num + (size_t)N_NODES*128;            // [4096,4]  (contiguous after num)
    float* h1      = denom + (size_t)N_NODES*4;            // [4096,32]
    float* h2      = h1 + (size_t)N_NODES*GCD;             // [4096,32]

    auto P = [&](int i){ return (const float*)d_in[i]; };

    branch_kernel<3><<<N_NODES,256,0,stream>>>(x, P(2),P(3),P(4),P(5),P(6),P(7),P(8),P(9),P(10),P(11), xf, 0);
    branch_kernel<5><<<N_NODES,256,0,stream>>>(x, P(12),P(13),P(14),P(15),P(16),P(17),P(18),P(19),P(20),P(21), xf, 16);
    branch_kernel<7><<<N_NODES,256,0,stream>>>(x, P(22),P(23),P(24),P(25),P(26),P(27),P(28),P(29),P(30),P(31), xf, 32);

    colsum_kernel<<<F3D,256,0,stream>>>(xf,colmean);
    gate_kernel<<<1,64,0,stream>>>(colmean,P(32),P(33),P(34),P(35),gate);
    scale_kernel<<<(N_NODES*F3D+255)/256,256,0,stream>>>(xf,gate);

    int etot = NGRAPH*epg + N_NODES;
    size_t accum_bytes = (size_t)(N_NODES*128 + N_NODES*4)*sizeof(float);

    // GAT layer 1
    hipMemsetAsync(num,0,accum_bytes,stream);
    gat_h_kernel<F3D><<<N_NODES,128,0,stream>>>(xf,P(36),P(37),P(38),hbuf,als,ald);
    edge_kernel<<<(etot+255)/256,256,0,stream>>>(ei,epg,als,ald,hbuf,num,denom);
    final1_kernel<<<N_NODES/2,64,0,stream>>>(num,denom,P(39),P(40),P(41),P(42),P(43),xf,P(44),P(45),h1);

    // GAT layer 2
    hipMemsetAsync(num,0,accum_bytes,stream);
    gat_h_kernel<GCD><<<N_NODES,128,0,stream>>>(h1,P(46),P(47),P(48),hbuf,als,ald);
    edge_kernel<<<(etot+255)/256,256,0,stream>>>(ei,epg,als,ald,hbuf,num,denom);
    final2_kernel<<<N_NODES/2,64,0,stream>>>(num,denom,P(49),P(50),P(51),P(52),P(53),h1,h2);

    pool_fc_kernel<<<NGRAPH,64,0,stream>>>(h2,P(54),P(55),(float*)d_out);
}

// Round 2
// 456.907 us; speedup vs baseline: 2.9039x; 2.9039x over previous
//
#include <hip/hip_runtime.h>
#include <math.h>

#define N_NODES 4096
#define T_LEN 1000
#define TCH 16
#define AHD 32
#define F3D 48
#define GCD 32
#define NPG 64
#define NGRAPH 64
#define BN_EPS 1e-5f

__device__ __forceinline__ float fast_rcp(float x){ return __builtin_amdgcn_rcpf(x); }
__device__ __forceinline__ float fast_tanh(float x){
    float e = __expf(2.0f*x);
    return 1.0f - 2.0f*fast_rcp(e+1.0f);
}
__device__ __forceinline__ float gelu_exact(float v){
    return 0.5f*v*(1.0f+erff(v*0.70710678118654752f));
}

// ---------------------------------------------------------------------------
// Branch: conv1d(k)+BN+GELU + attention pooling over T. One block per node.
// Attention loop restructured: w1 row loaded once per hidden unit as 4x b128
// (broadcast), reused across the thread's 4 positions -> 16x fewer LDS instrs.
// ---------------------------------------------------------------------------
template<int K>
__global__ __launch_bounds__(256)
void branch_kernel(const float* __restrict__ x,
                   const float* __restrict__ conv_w, const float* __restrict__ conv_b,
                   const float* __restrict__ bn_g, const float* __restrict__ bn_b,
                   const float* __restrict__ bn_m, const float* __restrict__ bn_v,
                   const float* __restrict__ aw1, const float* __restrict__ ab1,
                   const float* __restrict__ aw2, const float* __restrict__ ab2,
                   float* __restrict__ xf, int col0)
{
    __shared__ float xs[T_LEN+6];
    __shared__ float4 w1v[AHD*4];
    __shared__ float cws[TCH*K];
    __shared__ float shiftc[TCH];
    __shared__ float scl[TCH];
    __shared__ float b1s[AHD], w2s[AHD];
    __shared__ float redm[4], reds[4];
    __shared__ float fred[4][TCH];

    const int tid = threadIdx.x;
    const int node = blockIdx.x;
    const float* xrow = x + (size_t)node*T_LEN;

    for (int i=tid;i<T_LEN+6;i+=256){
        int q = i-3;
        xs[i] = (q>=0 && q<T_LEN) ? xrow[q] : 0.f;
    }
    if (tid<TCH){
        float s = bn_g[tid]*rsqrtf(bn_v[tid]+BN_EPS);
        scl[tid]=s;
        shiftc[tid] = (conv_b[tid]-bn_m[tid])*s + bn_b[tid];
    }
    if (tid<AHD){ b1s[tid]=ab1[tid]; w2s[tid]=aw2[tid]; }
    if (tid<AHD*4) w1v[tid] = ((const float4*)aw1)[tid];
    __syncthreads();
    for (int i=tid;i<TCH*K;i+=256) cws[i]=conv_w[i]*scl[i/K];
    const float b2v = ab2[0];
    __syncthreads();

    // conv + BN + GELU, 4 positions per thread
    float o[4][TCH];
    #pragma unroll
    for (int ii=0;ii<4;ii++){
        const int p = tid + ii*256;
        if (p < T_LEN){
            float xv[K];
            const int base = p + 3 - K/2;
            #pragma unroll
            for (int j=0;j<K;j++) xv[j]=xs[base+j];
            #pragma unroll
            for (int c=0;c<TCH;c++){
                float acc = shiftc[c];
                #pragma unroll
                for (int j=0;j<K;j++) acc += cws[c*K+j]*xv[j];
                o[ii][c] = gelu_exact(acc);
            }
        } else {
            #pragma unroll
            for (int c=0;c<TCH;c++) o[ii][c]=0.f;
        }
    }

    // attention scores: hidden-unit outer loop, w1 row hoisted, 4 pos inner
    float sv[4]={b2v,b2v,b2v,b2v};
    #pragma unroll 4
    for (int a=0;a<AHD;a++){
        const float4 wa0=w1v[a*4+0], wa1=w1v[a*4+1], wa2=w1v[a*4+2], wa3=w1v[a*4+3];
        const float b1a=b1s[a], w2a=w2s[a];
        #pragma unroll
        for (int ii=0;ii<4;ii++){
            float hh = b1a;
            hh += wa0.x*o[ii][0]+wa0.y*o[ii][1]+wa0.z*o[ii][2]+wa0.w*o[ii][3];
            hh += wa1.x*o[ii][4]+wa1.y*o[ii][5]+wa1.z*o[ii][6]+wa1.w*o[ii][7];
            hh += wa2.x*o[ii][8]+wa2.y*o[ii][9]+wa2.z*o[ii][10]+wa2.w*o[ii][11];
            hh += wa3.x*o[ii][12]+wa3.y*o[ii][13]+wa3.z*o[ii][14]+wa3.w*o[ii][15];
            sv[ii] += w2a*fast_tanh(hh);
        }
    }
    #pragma unroll
    for (int ii=0;ii<4;ii++) if (tid+ii*256 >= T_LEN) sv[ii]=-INFINITY;

    // block softmax over 1000 positions
    float m = fmaxf(fmaxf(sv[0],sv[1]),fmaxf(sv[2],sv[3]));
    #pragma unroll
    for (int off=32;off;off>>=1) m = fmaxf(m, __shfl_xor(m,off));
    const int wave=tid>>6, lane=tid&63;
    if (lane==0) redm[wave]=m;
    __syncthreads();
    const float bm = fmaxf(fmaxf(redm[0],redm[1]),fmaxf(redm[2],redm[3]));

    float e[4]; float ls=0.f;
    #pragma unroll
    for (int ii=0;ii<4;ii++){ e[ii]=__expf(sv[ii]-bm); ls+=e[ii]; }
    #pragma unroll
    for (int off=32;off;off>>=1) ls += __shfl_xor(ls,off);
    if (lane==0) reds[wave]=ls;
    __syncthreads();
    const float invS = fast_rcp(reds[0]+reds[1]+reds[2]+reds[3]);

    #pragma unroll
    for (int c=0;c<TCH;c++){
        float f = o[0][c]*e[0]+o[1][c]*e[1]+o[2][c]*e[2]+o[3][c]*e[3];
        #pragma unroll
        for (int off=32;off;off>>=1) f += __shfl_xor(f,off);
        if (lane==0) fred[wave][c]=f;
    }
    __syncthreads();
    if (tid<TCH){
        xf[(size_t)node*F3D + col0 + tid] =
            (fred[0][tid]+fred[1][tid]+fred[2][tid]+fred[3][tid])*invS;
    }
}

// ---------------------------------------------------------------------------
// SE block
// ---------------------------------------------------------------------------
__global__ __launch_bounds__(256)
void colsum_kernel(const float* __restrict__ xf, float* __restrict__ colmean){
    int col = blockIdx.x;
    int tid = threadIdx.x;
    float s=0.f;
    for (int i=tid;i<N_NODES;i+=256) s += xf[(size_t)i*F3D+col];
    #pragma unroll
    for (int off=32;off;off>>=1) s += __shfl_xor(s,off);
    __shared__ float red[4];
    if ((tid&63)==0) red[tid>>6]=s;
    __syncthreads();
    if (tid==0) colmean[col] = (red[0]+red[1]+red[2]+red[3])*(1.0f/(float)N_NODES);
}

__global__ __launch_bounds__(64)
void gate_kernel(const float* __restrict__ colmean,
                 const float* __restrict__ se_w1, const float* __restrict__ se_b1,
                 const float* __restrict__ se_w2, const float* __restrict__ se_b2,
                 float* __restrict__ gate){
    __shared__ float sq[F3D];
    __shared__ float g1[12];
    int tid=threadIdx.x;
    if (tid<F3D) sq[tid]=colmean[tid];
    __syncthreads();
    if (tid<12){
        float v=se_b1[tid];
        for (int j=0;j<F3D;j++) v += se_w1[tid*F3D+j]*sq[j];
        g1[tid]=gelu_exact(v);
    }
    __syncthreads();
    if (tid<F3D){
        float v=se_b2[tid];
        for (int m2=0;m2<12;m2++) v += se_w2[tid*12+m2]*g1[m2];
        gate[tid] = fast_rcp(1.0f+__expf(-v));
    }
}

// ---------------------------------------------------------------------------
// CSR build (per call; deterministic sizes)
// ---------------------------------------------------------------------------
__device__ __forceinline__ void edge_decode(const int* __restrict__ ei, int epg,
                                            int e, int be, int& src, int& dst){
    if (e < be){ int b=e/epg, j=e-b*epg; src=ei[j]+b*NPG; dst=ei[epg+j]+b*NPG; }
    else { src=dst=e-be; }
}

__global__ __launch_bounds__(256)
void edge_count(const int* __restrict__ ei, int epg, int* __restrict__ deg){
    int e = blockIdx.x*256+threadIdx.x;
    int be = NGRAPH*epg, total = be + N_NODES;
    if (e>=total) return;
    int s,d; edge_decode(ei,epg,e,be,s,d);
    atomicAdd(&deg[d],1);
}

__global__ __launch_bounds__(1024)
void scan_kernel(const int* __restrict__ deg, int* __restrict__ rowstart,
                 int* __restrict__ cursor){
    __shared__ int part[1024];
    int tid=threadIdx.x;
    int v0=deg[tid*4],v1=deg[tid*4+1],v2=deg[tid*4+2],v3=deg[tid*4+3];
    part[tid]=v0+v1+v2+v3;
    __syncthreads();
    for (int off=1;off<1024;off<<=1){
        int t=(tid>=off)?part[tid-off]:0;
        __syncthreads();
        part[tid]+=t;
        __syncthreads();
    }
    int base=(tid>0)?part[tid-1]:0;
    int r0=base, r1=r0+v0, r2=r1+v1, r3=r2+v2;
    rowstart[tid*4]=r0; rowstart[tid*4+1]=r1; rowstart[tid*4+2]=r2; rowstart[tid*4+3]=r3;
    cursor[tid*4]=r0;   cursor[tid*4+1]=r1;   cursor[tid*4+2]=r2;   cursor[tid*4+3]=r3;
    if (tid==1023) rowstart[4096]=part[1023];
}

__global__ __launch_bounds__(256)
void edge_fill(const int* __restrict__ ei, int epg, int* __restrict__ cursor,
               int* __restrict__ cols){
    int e = blockIdx.x*256+threadIdx.x;
    int be = NGRAPH*epg, total = be + N_NODES;
    if (e>=total) return;
    int s,d; edge_decode(ei,epg,e,be,s,d);
    int pos = atomicAdd(&cursor[d],1);
    cols[pos]=s;
}

// ---------------------------------------------------------------------------
// GAT: node transform h = x @ W.T plus attention logits
// ---------------------------------------------------------------------------
template<int INF, bool GATED>
__global__ __launch_bounds__(128)
void gat_h_kernel(const float* __restrict__ xin_g, const float* __restrict__ gate,
                  const float* __restrict__ W,
                  const float* __restrict__ a_src, const float* __restrict__ a_dst,
                  float* __restrict__ hbuf, float* __restrict__ als, float* __restrict__ ald){
    __shared__ float xin[INF];
    __shared__ float hs[128];
    int node=blockIdx.x, tid=threadIdx.x;
    if (tid<INF){
        float v = xin_g[(size_t)node*INF+tid];
        if (GATED) v *= gate[tid];
        xin[tid]=v;
    }
    __syncthreads();
    float acc=0.f;
    const float* wr = W + (size_t)tid*INF;
    #pragma unroll
    for (int j=0;j<INF;j++) acc += wr[j]*xin[j];
    hs[tid]=acc;
    hbuf[(size_t)node*128+tid]=acc;
    __syncthreads();
    if (tid<8){
        int head=tid&3;
        const float* av = (tid<4)? a_src : a_dst;
        float s=0.f;
        for (int c=0;c<GCD;c++) s += hs[head*GCD+c]*av[head*GCD+c];
        if (tid<4) als[(size_t)node*4+head]=s;
        else       ald[(size_t)node*4+head]=s;
    }
}

// ---------------------------------------------------------------------------
// CSR gather + softmax + head-mean + BN (+skip) + GELU, fused.  8 nodes/block.
// ---------------------------------------------------------------------------
__global__ __launch_bounds__(256)
void gat_gather1(const int* __restrict__ rowstart, const int* __restrict__ cols,
                 const float* __restrict__ als, const float* __restrict__ ald,
                 const float* __restrict__ hbuf,
                 const float* __restrict__ bias,
                 const float* __restrict__ bn_g, const float* __restrict__ bn_b,
                 const float* __restrict__ bn_m, const float* __restrict__ bn_v,
                 const float* __restrict__ xf, const float* __restrict__ gate,
                 const float* __restrict__ skip_w, const float* __restrict__ skip_b,
                 float* __restrict__ h1){
    const int node = blockIdx.x*8 + (threadIdx.x>>5);
    const int c = threadIdx.x&31;
    const float4 ad = ((const float4*)ald)[node];
    float n0=0,n1=0,n2=0,n3=0,d0=0,d1=0,d2=0,d3=0;
    const int s0=rowstart[node], s1=rowstart[node+1];
    for (int e=s0;e<s1;e++){
        const int src=cols[e];
        const float4 as=((const float4*)als)[src];
        float e0=as.x+ad.x; e0=e0>0.f?e0:0.2f*e0; float w0=__expf(e0);
        float e1=as.y+ad.y; e1=e1>0.f?e1:0.2f*e1; float w1=__expf(e1);
        float e2=as.z+ad.z; e2=e2>0.f?e2:0.2f*e2; float w2=__expf(e2);
        float e3=as.w+ad.w; e3=e3>0.f?e3:0.2f*e3; float w3=__expf(e3);
        const float* hr=&hbuf[(size_t)src*128];
        n0+=w0*hr[c]; n1+=w1*hr[32+c]; n2+=w2*hr[64+c]; n3+=w3*hr[96+c];
        d0+=w0; d1+=w1; d2+=w2; d3+=w3;
    }
    float acc = 0.25f*(n0*fast_rcp(d0)+n1*fast_rcp(d1)+n2*fast_rcp(d2)+n3*fast_rcp(d3)) + bias[c];
    acc = (acc-bn_m[c])*rsqrtf(bn_v[c]+BN_EPS)*bn_g[c]+bn_b[c];
    float sk = skip_b[c];
    const float* xr=&xf[(size_t)node*F3D];
    #pragma unroll
    for (int j=0;j<F3D;j++) sk += xr[j]*gate[j]*skip_w[c*F3D+j];
    h1[(size_t)node*GCD+c]=gelu_exact(acc+sk);
}

__global__ __launch_bounds__(256)
void gat_gather2(const int* __restrict__ rowstart, const int* __restrict__ cols,
                 const float* __restrict__ als, const float* __restrict__ ald,
                 const float* __restrict__ hbuf,
                 const float* __restrict__ bias,
                 const float* __restrict__ bn_g, const float* __restrict__ bn_b,
                 const float* __restrict__ bn_m, const float* __restrict__ bn_v,
                 const float* __restrict__ h1, float* __restrict__ h2){
    const int node = blockIdx.x*8 + (threadIdx.x>>5);
    const int c = threadIdx.x&31;
    const float4 ad = ((const float4*)ald)[node];
    float n0=0,n1=0,n2=0,n3=0,d0=0,d1=0,d2=0,d3=0;
    const int s0=rowstart[node], s1=rowstart[node+1];
    for (int e=s0;e<s1;e++){
        const int src=cols[e];
        const float4 as=((const float4*)als)[src];
        float e0=as.x+ad.x; e0=e0>0.f?e0:0.2f*e0; float w0=__expf(e0);
        float e1=as.y+ad.y; e1=e1>0.f?e1:0.2f*e1; float w1=__expf(e1);
        float e2=as.z+ad.z; e2=e2>0.f?e2:0.2f*e2; float w2=__expf(e2);
        float e3=as.w+ad.w; e3=e3>0.f?e3:0.2f*e3; float w3=__expf(e3);
        const float* hr=&hbuf[(size_t)src*128];
        n0+=w0*hr[c]; n1+=w1*hr[32+c]; n2+=w2*hr[64+c]; n3+=w3*hr[96+c];
        d0+=w0; d1+=w1; d2+=w2; d3+=w3;
    }
    float acc = 0.25f*(n0*fast_rcp(d0)+n1*fast_rcp(d1)+n2*fast_rcp(d2)+n3*fast_rcp(d3)) + bias[c];
    acc = (acc-bn_m[c])*rsqrtf(bn_v[c]+BN_EPS)*bn_g[c]+bn_b[c];
    float v = acc + h1[(size_t)node*GCD+c];
    h2[(size_t)node*GCD+c]=gelu_exact(v);
}

__global__ __launch_bounds__(64)
void pool_fc_kernel(const float* __restrict__ h2, const float* __restrict__ fc_w,
                    const float* __restrict__ fc_b, float* __restrict__ out){
    int g = blockIdx.x;
    int tid = threadIdx.x;
    __shared__ float part[2][GCD];
    __shared__ float pool[GCD];
    int c = tid&31, hf = tid>>5;
    float acc=0.f;
    for (int i=hf*32;i<hf*32+32;i++) acc += h2[((size_t)(g*NPG+i))*GCD+c];
    part[hf][c]=acc;
    __syncthreads();
    if (tid<GCD) pool[tid]=(part[0][tid]+part[1][tid])*(1.0f/(float)NPG);
    __syncthreads();
    if (tid<2){
        float o=fc_b[tid];
        for (int cc=0;cc<GCD;cc++) o += pool[cc]*fc_w[tid*GCD+cc];
        out[g*2+tid]=o;
    }
}

// ---------------------------------------------------------------------------
extern "C" void kernel_launch(void* const* d_in, const int* in_sizes, int n_in,
                              void* d_out, int out_size, void* d_ws, size_t ws_size,
                              hipStream_t stream){
    const float* x = (const float*)d_in[0];
    const int* ei = (const int*)d_in[1];
    const int epg = in_sizes[1]/2;

    float* ws = (float*)d_ws;
    float* xf      = ws;                                   // [4096,48]
    float* colmean = xf + (size_t)N_NODES*F3D;             // 64
    float* gate    = colmean + 64;                         // 64
    float* hbuf    = gate + 64;                            // [4096,128]
    float* als     = hbuf + (size_t)N_NODES*128;           // [4096,4]
    float* ald     = als + (size_t)N_NODES*4;              // [4096,4]
    float* h1      = ald + (size_t)N_NODES*4;              // [4096,32]
    float* h2      = h1 + (size_t)N_NODES*GCD;             // [4096,32]
    int*   deg      = (int*)(h2 + (size_t)N_NODES*GCD);    // [4096]
    int*   rowstart = deg + N_NODES;                       // [4097]
    int*   cursor   = rowstart + N_NODES + 1;              // [4096]
    int*   cols     = cursor + N_NODES;                    // [~41K]

    auto P = [&](int i){ return (const float*)d_in[i]; };

    // CSR build (independent of branch compute)
    const int etot = NGRAPH*epg + N_NODES;
    hipMemsetAsync(deg, 0, (size_t)N_NODES*sizeof(int), stream);
    edge_count<<<(etot+255)/256,256,0,stream>>>(ei,epg,deg);
    scan_kernel<<<1,1024,0,stream>>>(deg,rowstart,cursor);
    edge_fill<<<(etot+255)/256,256,0,stream>>>(ei,epg,cursor,cols);

    branch_kernel<3><<<N_NODES,256,0,stream>>>(x, P(2),P(3),P(4),P(5),P(6),P(7),P(8),P(9),P(10),P(11), xf, 0);
    branch_kernel<5><<<N_NODES,256,0,stream>>>(x, P(12),P(13),P(14),P(15),P(16),P(17),P(18),P(19),P(20),P(21), xf, 16);
    branch_kernel<7><<<N_NODES,256,0,stream>>>(x, P(22),P(23),P(24),P(25),P(26),P(27),P(28),P(29),P(30),P(31), xf, 32);

    colsum_kernel<<<F3D,256,0,stream>>>(xf,colmean);
    gate_kernel<<<1,64,0,stream>>>(colmean,P(32),P(33),P(34),P(35),gate);

    // GAT layer 1 (gate applied on load; skip fused into gather)
    gat_h_kernel<F3D,true><<<N_NODES,128,0,stream>>>(xf,gate,P(36),P(37),P(38),hbuf,als,ald);
    gat_gather1<<<N_NODES/8,256,0,stream>>>(rowstart,cols,als,ald,hbuf,
                                            P(39),P(40),P(41),P(42),P(43),
                                            xf,gate,P(44),P(45),h1);

    // GAT layer 2
    gat_h_kernel<GCD,false><<<N_NODES,128,0,stream>>>(h1,nullptr,P(46),P(47),P(48),hbuf,als,ald);
    gat_gather2<<<N_NODES/8,256,0,stream>>>(rowstart,cols,als,ald,hbuf,
                                            P(49),P(50),P(51),P(52),P(53),
                                            h1,h2);

    pool_fc_kernel<<<NGRAPH,64,0,stream>>>(h2,P(54),P(55),(float*)d_out);
}

// Round 3
// 398.768 us; speedup vs baseline: 3.3272x; 1.1458x over previous
//
#include <hip/hip_runtime.h>
#include <math.h>

#define N_NODES 4096
#define T_LEN 1000
#define TCH 16
#define AHD 32
#define F3D 48
#define GCD 32
#define NPG 64
#define NGRAPH 64
#define BN_EPS 1e-5f

typedef _Float16 half4_t __attribute__((ext_vector_type(4)));
typedef float float4_t __attribute__((ext_vector_type(4)));

__device__ __forceinline__ float fast_rcp(float x){ return __builtin_amdgcn_rcpf(x); }
__device__ __forceinline__ float fast_tanh(float x){
    float e = __expf(2.0f*x);
    return 1.0f - 2.0f*fast_rcp(e+1.0f);
}
__device__ __forceinline__ float gelu_exact(float v){
    return 0.5f*v*(1.0f+erff(v*0.70710678118654752f));
}

// ---------------------------------------------------------------------------
// Branch: conv1d(k)+BN+GELU (fp32 regs) + MFMA fp16 attention einsum + softmax
// pooling. One block (256 thr) per node.
// ---------------------------------------------------------------------------
template<int K>
__global__ __launch_bounds__(256)
void branch_kernel(const float* __restrict__ x,
                   const float* __restrict__ conv_w, const float* __restrict__ conv_b,
                   const float* __restrict__ bn_g, const float* __restrict__ bn_b,
                   const float* __restrict__ bn_m, const float* __restrict__ bn_v,
                   const float* __restrict__ aw1, const float* __restrict__ ab1,
                   const float* __restrict__ aw2, const float* __restrict__ ab2,
                   float* __restrict__ xf, int col0)
{
    __shared__ float xs[T_LEN+8];
    __shared__ __align__(16) _Float16 o_h[1024*TCH];   // 32 KB, [pos][ch]
    __shared__ float s_arr[1024];
    __shared__ float cws[TCH*K];
    __shared__ float shiftc[TCH];
    __shared__ float scl[TCH];
    __shared__ float redm[4], reds[4];
    __shared__ float fred[4][TCH];

    const int tid = threadIdx.x;
    const int node = blockIdx.x;
    const float* xrow = x + (size_t)node*T_LEN;

    for (int i=tid;i<T_LEN+6;i+=256){
        int q = i-3;
        xs[i] = (q>=0 && q<T_LEN) ? xrow[q] : 0.f;
    }
    if (tid<TCH){
        float s = bn_g[tid]*rsqrtf(bn_v[tid]+BN_EPS);
        scl[tid]=s;
        shiftc[tid] = (conv_b[tid]-bn_m[tid])*s + bn_b[tid];
    }
    __syncthreads();
    for (int i=tid;i<TCH*K;i+=256) cws[i]=conv_w[i]*scl[i/K];
    __syncthreads();

    // ---- conv + BN + GELU: 4 positions per thread, fp32 registers ----
    float o[4][TCH];
    #pragma unroll
    for (int ii=0;ii<4;ii++){
        const int p = tid + ii*256;
        if (p < T_LEN){
            float xv[K];
            const int base = p + 3 - K/2;
            #pragma unroll
            for (int j=0;j<K;j++) xv[j]=xs[base+j];
            #pragma unroll
            for (int c=0;c<TCH;c++){
                float acc = shiftc[c];
                #pragma unroll
                for (int j=0;j<K;j++) acc += cws[c*K+j]*xv[j];
                o[ii][c] = gelu_exact(acc);
            }
        } else {
            #pragma unroll
            for (int c=0;c<TCH;c++) o[ii][c]=0.f;
        }
    }

    // ---- pack o -> LDS fp16 [pos][ch] ----
    #pragma unroll
    for (int ii=0;ii<4;ii++){
        const int p = tid + ii*256;
        union { _Float16 h[16]; uint4 u[2]; } pk;
        #pragma unroll
        for (int c=0;c<TCH;c++) pk.h[c] = (_Float16)o[ii][c];
        uint4* dst = (uint4*)&o_h[p*TCH];
        dst[0]=pk.u[0]; dst[1]=pk.u[1];
    }
    __syncthreads();

    // ---- MFMA einsum: h[32,1024] = w1[32,16] x o[16,1024] (+b1), tanh, w2 ----
    const int lane = tid&63, wave = tid>>6;
    const int mrow = lane&15;           // A row / B col / C col
    const int kg   = (lane>>4)*4;       // A/B k base, C row base

    float4_t wr0 = *(const float4_t*)&aw1[(size_t)mrow*TCH + kg];
    float4_t wr1 = *(const float4_t*)&aw1[(size_t)(mrow+16)*TCH + kg];
    half4_t a0, a1;
    #pragma unroll
    for (int r=0;r<4;r++){ a0[r]=(_Float16)wr0[r]; a1[r]=(_Float16)wr1[r]; }
    const float4_t c0 = *(const float4_t*)&ab1[kg];
    const float4_t c1 = *(const float4_t*)&ab1[16+kg];
    const float4_t w20 = *(const float4_t*)&aw2[kg];
    const float4_t w21 = *(const float4_t*)&aw2[16+kg];
    const float b2v = ab2[0];
    const float w2sum8 = w20[0]+w20[1]+w20[2]+w20[3]+w21[0]+w21[1]+w21[2]+w21[3];
    const float TWO_LOG2E = 2.8853900817779268f;  // 2*log2(e)

    #pragma unroll 2
    for (int i=0;i<16;i++){
        const int t = wave*16 + i;
        const int pos = t*16 + mrow;
        half4_t b = *(const half4_t*)&o_h[(size_t)pos*TCH + kg];
        float4_t acc0 = __builtin_amdgcn_mfma_f32_16x16x16f16(a0,b,c0,0,0,0);
        float4_t acc1 = __builtin_amdgcn_mfma_f32_16x16x16f16(a1,b,c1,0,0,0);
        // sum w2*tanh(h) over this lane's 8 rows: w2sum8 - 2*sum w2*rcp(exp2(h*2log2e)+1)
        float accr = 0.f;
        #pragma unroll
        for (int r=0;r<4;r++){
            accr += w20[r]*fast_rcp(__builtin_amdgcn_exp2f(acc0[r]*TWO_LOG2E)+1.0f);
            accr += w21[r]*fast_rcp(__builtin_amdgcn_exp2f(acc1[r]*TWO_LOG2E)+1.0f);
        }
        float part = w2sum8 - 2.0f*accr;
        part += __shfl_xor(part,16);
        part += __shfl_xor(part,32);
        float sfin = (pos < T_LEN) ? (part + b2v) : -INFINITY;
        if (lane<16) s_arr[t*16+lane] = sfin;
    }
    __syncthreads();

    // ---- block softmax over 1000 positions + weighted pool (fp32) ----
    float sv[4];
    #pragma unroll
    for (int ii=0;ii<4;ii++) sv[ii] = s_arr[tid+ii*256];

    float m = fmaxf(fmaxf(sv[0],sv[1]),fmaxf(sv[2],sv[3]));
    #pragma unroll
    for (int off=32;off;off>>=1) m = fmaxf(m, __shfl_xor(m,off));
    if (lane==0) redm[wave]=m;
    __syncthreads();
    const float bm = fmaxf(fmaxf(redm[0],redm[1]),fmaxf(redm[2],redm[3]));

    float e[4]; float ls=0.f;
    #pragma unroll
    for (int ii=0;ii<4;ii++){ e[ii]=__expf(sv[ii]-bm); ls+=e[ii]; }
    #pragma unroll
    for (int off=32;off;off>>=1) ls += __shfl_xor(ls,off);
    if (lane==0) reds[wave]=ls;
    __syncthreads();
    const float invS = fast_rcp(reds[0]+reds[1]+reds[2]+reds[3]);

    #pragma unroll
    for (int c=0;c<TCH;c++){
        float f = o[0][c]*e[0]+o[1][c]*e[1]+o[2][c]*e[2]+o[3][c]*e[3];
        #pragma unroll
        for (int off=32;off;off>>=1) f += __shfl_xor(f,off);
        if (lane==0) fred[wave][c]=f;
    }
    __syncthreads();
    if (tid<TCH){
        xf[(size_t)node*F3D + col0 + tid] =
            (fred[0][tid]+fred[1][tid]+fred[2][tid]+fred[3][tid])*invS;
    }
}

// ---------------------------------------------------------------------------
// SE block
// ---------------------------------------------------------------------------
__global__ __launch_bounds__(256)
void colsum_kernel(const float* __restrict__ xf, float* __restrict__ colmean){
    int col = blockIdx.x;
    int tid = threadIdx.x;
    float s=0.f;
    for (int i=tid;i<N_NODES;i+=256) s += xf[(size_t)i*F3D+col];
    #pragma unroll
    for (int off=32;off;off>>=1) s += __shfl_xor(s,off);
    __shared__ float red[4];
    if ((tid&63)==0) red[tid>>6]=s;
    __syncthreads();
    if (tid==0) colmean[col] = (red[0]+red[1]+red[2]+red[3])*(1.0f/(float)N_NODES);
}

__global__ __launch_bounds__(64)
void gate_kernel(const float* __restrict__ colmean,
                 const float* __restrict__ se_w1, const float* __restrict__ se_b1,
                 const float* __restrict__ se_w2, const float* __restrict__ se_b2,
                 float* __restrict__ gate){
    __shared__ float sq[F3D];
    __shared__ float g1[12];
    int tid=threadIdx.x;
    if (tid<F3D) sq[tid]=colmean[tid];
    __syncthreads();
    if (tid<12){
        float v=se_b1[tid];
        for (int j=0;j<F3D;j++) v += se_w1[tid*F3D+j]*sq[j];
        g1[tid]=gelu_exact(v);
    }
    __syncthreads();
    if (tid<F3D){
        float v=se_b2[tid];
        for (int m2=0;m2<12;m2++) v += se_w2[tid*12+m2]*g1[m2];
        gate[tid] = fast_rcp(1.0f+__expf(-v));
    }
}

// ---------------------------------------------------------------------------
// CSR build
// ---------------------------------------------------------------------------
__device__ __forceinline__ void edge_decode(const int* __restrict__ ei, int epg,
                                            int e, int be, int& src, int& dst){
    if (e < be){ int b=e/epg, j=e-b*epg; src=ei[j]+b*NPG; dst=ei[epg+j]+b*NPG; }
    else { src=dst=e-be; }
}

__global__ __launch_bounds__(256)
void edge_count(const int* __restrict__ ei, int epg, int* __restrict__ deg){
    int e = blockIdx.x*256+threadIdx.x;
    int be = NGRAPH*epg, total = be + N_NODES;
    if (e>=total) return;
    int s,d; edge_decode(ei,epg,e,be,s,d);
    atomicAdd(&deg[d],1);
}

__global__ __launch_bounds__(1024)
void scan_kernel(const int* __restrict__ deg, int* __restrict__ rowstart,
                 int* __restrict__ cursor){
    __shared__ int part[1024];
    int tid=threadIdx.x;
    int v0=deg[tid*4],v1=deg[tid*4+1],v2=deg[tid*4+2],v3=deg[tid*4+3];
    part[tid]=v0+v1+v2+v3;
    __syncthreads();
    for (int off=1;off<1024;off<<=1){
        int t=(tid>=off)?part[tid-off]:0;
        __syncthreads();
        part[tid]+=t;
        __syncthreads();
    }
    int base=(tid>0)?part[tid-1]:0;
    int r0=base, r1=r0+v0, r2=r1+v1, r3=r2+v2;
    rowstart[tid*4]=r0; rowstart[tid*4+1]=r1; rowstart[tid*4+2]=r2; rowstart[tid*4+3]=r3;
    cursor[tid*4]=r0;   cursor[tid*4+1]=r1;   cursor[tid*4+2]=r2;   cursor[tid*4+3]=r3;
    if (tid==1023) rowstart[4096]=part[1023];
}

__global__ __launch_bounds__(256)
void edge_fill(const int* __restrict__ ei, int epg, int* __restrict__ cursor,
               int* __restrict__ cols){
    int e = blockIdx.x*256+threadIdx.x;
    int be = NGRAPH*epg, total = be + N_NODES;
    if (e>=total) return;
    int s,d; edge_decode(ei,epg,e,be,s,d);
    int pos = atomicAdd(&cursor[d],1);
    cols[pos]=s;
}

// ---------------------------------------------------------------------------
// GAT: node transform h = x @ W.T plus attention logits
// ---------------------------------------------------------------------------
template<int INF, bool GATED>
__global__ __launch_bounds__(128)
void gat_h_kernel(const float* __restrict__ xin_g, const float* __restrict__ gate,
                  const float* __restrict__ W,
                  const float* __restrict__ a_src, const float* __restrict__ a_dst,
                  float* __restrict__ hbuf, float* __restrict__ als, float* __restrict__ ald){
    __shared__ float xin[INF];
    __shared__ float hs[128];
    int node=blockIdx.x, tid=threadIdx.x;
    if (tid<INF){
        float v = xin_g[(size_t)node*INF+tid];
        if (GATED) v *= gate[tid];
        xin[tid]=v;
    }
    __syncthreads();
    float acc=0.f;
    const float* wr = W + (size_t)tid*INF;
    #pragma unroll
    for (int j=0;j<INF;j++) acc += wr[j]*xin[j];
    hs[tid]=acc;
    hbuf[(size_t)node*128+tid]=acc;
    __syncthreads();
    if (tid<8){
        int head=tid&3;
        const float* av = (tid<4)? a_src : a_dst;
        float s=0.f;
        for (int c=0;c<GCD;c++) s += hs[head*GCD+c]*av[head*GCD+c];
        if (tid<4) als[(size_t)node*4+head]=s;
        else       ald[(size_t)node*4+head]=s;
    }
}

// ---------------------------------------------------------------------------
// CSR gather + softmax + head-mean + BN (+skip) + GELU, fused. 8 nodes/block.
// ---------------------------------------------------------------------------
__global__ __launch_bounds__(256)
void gat_gather1(const int* __restrict__ rowstart, const int* __restrict__ cols,
                 const float* __restrict__ als, const float* __restrict__ ald,
                 const float* __restrict__ hbuf,
                 const float* __restrict__ bias,
                 const float* __restrict__ bn_g, const float* __restrict__ bn_b,
                 const float* __restrict__ bn_m, const float* __restrict__ bn_v,
                 const float* __restrict__ xf, const float* __restrict__ gate,
                 const float* __restrict__ skip_w, const float* __restrict__ skip_b,
                 float* __restrict__ h1){
    const int node = blockIdx.x*8 + (threadIdx.x>>5);
    const int c = threadIdx.x&31;
    const float4 ad = ((const float4*)ald)[node];
    float n0=0,n1=0,n2=0,n3=0,d0=0,d1=0,d2=0,d3=0;
    const int s0=rowstart[node], s1=rowstart[node+1];
    for (int e=s0;e<s1;e++){
        const int src=cols[e];
        const float4 as=((const float4*)als)[src];
        float e0=as.x+ad.x; e0=e0>0.f?e0:0.2f*e0; float w0=__expf(e0);
        float e1=as.y+ad.y; e1=e1>0.f?e1:0.2f*e1; float w1=__expf(e1);
        float e2=as.z+ad.z; e2=e2>0.f?e2:0.2f*e2; float w2=__expf(e2);
        float e3=as.w+ad.w; e3=e3>0.f?e3:0.2f*e3; float w3=__expf(e3);
        const float* hr=&hbuf[(size_t)src*128];
        n0+=w0*hr[c]; n1+=w1*hr[32+c]; n2+=w2*hr[64+c]; n3+=w3*hr[96+c];
        d0+=w0; d1+=w1; d2+=w2; d3+=w3;
    }
    float acc = 0.25f*(n0*fast_rcp(d0)+n1*fast_rcp(d1)+n2*fast_rcp(d2)+n3*fast_rcp(d3)) + bias[c];
    acc = (acc-bn_m[c])*rsqrtf(bn_v[c]+BN_EPS)*bn_g[c]+bn_b[c];
    float sk = skip_b[c];
    const float* xr=&xf[(size_t)node*F3D];
    #pragma unroll
    for (int j=0;j<F3D;j++) sk += xr[j]*gate[j]*skip_w[c*F3D+j];
    h1[(size_t)node*GCD+c]=gelu_exact(acc+sk);
}

__global__ __launch_bounds__(256)
void gat_gather2(const int* __restrict__ rowstart, const int* __restrict__ cols,
                 const float* __restrict__ als, const float* __restrict__ ald,
                 const float* __restrict__ hbuf,
                 const float* __restrict__ bias,
                 const float* __restrict__ bn_g, const float* __restrict__ bn_b,
                 const float* __restrict__ bn_m, const float* __restrict__ bn_v,
                 const float* __restrict__ h1, float* __restrict__ h2){
    const int node = blockIdx.x*8 + (threadIdx.x>>5);
    const int c = threadIdx.x&31;
    const float4 ad = ((const float4*)ald)[node];
    float n0=0,n1=0,n2=0,n3=0,d0=0,d1=0,d2=0,d3=0;
    const int s0=rowstart[node], s1=rowstart[node+1];
    for (int e=s0;e<s1;e++){
        const int src=cols[e];
        const float4 as=((const float4*)als)[src];
        float e0=as.x+ad.x; e0=e0>0.f?e0:0.2f*e0; float w0=__expf(e0);
        float e1=as.y+ad.y; e1=e1>0.f?e1:0.2f*e1; float w1=__expf(e1);
        float e2=as.z+ad.z; e2=e2>0.f?e2:0.2f*e2; float w2=__expf(e2);
        float e3=as.w+ad.w; e3=e3>0.f?e3:0.2f*e3; float w3=__expf(e3);
        const float* hr=&hbuf[(size_t)src*128];
        n0+=w0*hr[c]; n1+=w1*hr[32+c]; n2+=w2*hr[64+c]; n3+=w3*hr[96+c];
        d0+=w0; d1+=w1; d2+=w2; d3+=w3;
    }
    float acc = 0.25f*(n0*fast_rcp(d0)+n1*fast_rcp(d1)+n2*fast_rcp(d2)+n3*fast_rcp(d3)) + bias[c];
    acc = (acc-bn_m[c])*rsqrtf(bn_v[c]+BN_EPS)*bn_g[c]+bn_b[c];
    float v = acc + h1[(size_t)node*GCD+c];
    h2[(size_t)node*GCD+c]=gelu_exact(v);
}

__global__ __launch_bounds__(64)
void pool_fc_kernel(const float* __restrict__ h2, const float* __restrict__ fc_w,
                    const float* __restrict__ fc_b, float* __restrict__ out){
    int g = blockIdx.x;
    int tid = threadIdx.x;
    __shared__ float part[2][GCD];
    __shared__ float pool[GCD];
    int c = tid&31, hf = tid>>5;
    float acc=0.f;
    for (int i=hf*32;i<hf*32+32;i++) acc += h2[((size_t)(g*NPG+i))*GCD+c];
    part[hf][c]=acc;
    __syncthreads();
    if (tid<GCD) pool[tid]=(part[0][tid]+part[1][tid])*(1.0f/(float)NPG);
    __syncthreads();
    if (tid<2){
        float o=fc_b[tid];
        for (int cc=0;cc<GCD;cc++) o += pool[cc]*fc_w[tid*GCD+cc];
        out[g*2+tid]=o;
    }
}

// ---------------------------------------------------------------------------
extern "C" void kernel_launch(void* const* d_in, const int* in_sizes, int n_in,
                              void* d_out, int out_size, void* d_ws, size_t ws_size,
                              hipStream_t stream){
    const float* x = (const float*)d_in[0];
    const int* ei = (const int*)d_in[1];
    const int epg = in_sizes[1]/2;

    float* ws = (float*)d_ws;
    float* xf      = ws;                                   // [4096,48]
    float* colmean = xf + (size_t)N_NODES*F3D;             // 64
    float* gate    = colmean + 64;                         // 64
    float* hbuf    = gate + 64;                            // [4096,128]
    float* als     = hbuf + (size_t)N_NODES*128;           // [4096,4]
    float* ald     = als + (size_t)N_NODES*4;              // [4096,4]
    float* h1      = ald + (size_t)N_NODES*4;              // [4096,32]
    float* h2      = h1 + (size_t)N_NODES*GCD;             // [4096,32]
    int*   deg      = (int*)(h2 + (size_t)N_NODES*GCD);    // [4096]
    int*   rowstart = deg + N_NODES;                       // [4097]
    int*   cursor   = rowstart + N_NODES + 1;              // [4096]
    int*   cols     = cursor + N_NODES;                    // [~41K]

    auto P = [&](int i){ return (const float*)d_in[i]; };

    const int etot = NGRAPH*epg + N_NODES;
    hipMemsetAsync(deg, 0, (size_t)N_NODES*sizeof(int), stream);
    edge_count<<<(etot+255)/256,256,0,stream>>>(ei,epg,deg);
    scan_kernel<<<1,1024,0,stream>>>(deg,rowstart,cursor);
    edge_fill<<<(etot+255)/256,256,0,stream>>>(ei,epg,cursor,cols);

    branch_kernel<3><<<N_NODES,256,0,stream>>>(x, P(2),P(3),P(4),P(5),P(6),P(7),P(8),P(9),P(10),P(11), xf, 0);
    branch_kernel<5><<<N_NODES,256,0,stream>>>(x, P(12),P(13),P(14),P(15),P(16),P(17),P(18),P(19),P(20),P(21), xf, 16);
    branch_kernel<7><<<N_NODES,256,0,stream>>>(x, P(22),P(23),P(24),P(25),P(26),P(27),P(28),P(29),P(30),P(31), xf, 32);

    colsum_kernel<<<F3D,256,0,stream>>>(xf,colmean);
    gate_kernel<<<1,64,0,stream>>>(colmean,P(32),P(33),P(34),P(35),gate);

    gat_h_kernel<F3D,true><<<N_NODES,128,0,stream>>>(xf,gate,P(36),P(37),P(38),hbuf,als,ald);
    gat_gather1<<<N_NODES/8,256,0,stream>>>(rowstart,cols,als,ald,hbuf,
                                            P(39),P(40),P(41),P(42),P(43),
                                            xf,gate,P(44),P(45),h1);

    gat_h_kernel<GCD,false><<<N_NODES,128,0,stream>>>(h1,nullptr,P(46),P(47),P(48),hbuf,als,ald);
    gat_gather2<<<N_NODES/8,256,0,stream>>>(rowstart,cols,als,ald,hbuf,
                                            P(49),P(50),P(51),P(52),P(53),
                                            h1,h2);

    pool_fc_kernel<<<NGRAPH,64,0,stream>>>(h2,P(54),P(55),(float*)d_out);
}

// Round 4
// 263.468 us; speedup vs baseline: 5.0359x; 1.5135x over previous
//
#include <hip/hip_runtime.h>
#include <math.h>

#define N_NODES 4096
#define T_LEN 1000
#define TCH 16
#define AHD 32
#define F3D 48
#define GCD 32
#define NPG 64
#define NGRAPH 64
#define BN_EPS 1e-5f

typedef _Float16 half4_t __attribute__((ext_vector_type(4)));
typedef float float4_t __attribute__((ext_vector_type(4)));

__device__ __forceinline__ float fast_rcp(float x){ return __builtin_amdgcn_rcpf(x); }
__device__ __forceinline__ float gelu_exact(float v){
    return 0.5f*v*(1.0f+erff(v*0.70710678118654752f));
}
// A&S 7.1.26 erf-based GELU: abs err <= 1.5e-7, ~12 VALU (1 rcp + 1 exp2)
__device__ __forceinline__ float fast_gelu(float v){
    float av = fabsf(v);
    float z  = av*0.70710678118654752f;
    float t  = fast_rcp(1.0f + 0.3275911f*z);
    float poly = t*(0.254829592f + t*(-0.284496736f + t*(1.421413741f + t*(-1.453152027f + t*1.061405429f))));
    float ez = __builtin_amdgcn_exp2f(z*z*-1.4426950408889634f);
    float erfabs = 1.0f - poly*ez;
    return 0.5f*(v + av*erfabs);
}

struct BranchParams {
    const float* conv_w; const float* conv_b;
    const float* bn_g; const float* bn_b; const float* bn_m; const float* bn_v;
    const float* aw1; const float* ab1; const float* aw2; const float* ab2;
    int K; int col0;
};

// ---------------------------------------------------------------------------
// Unified branch kernel: conv-as-MFMA (bias via C operand) -> GELU -> einsum
// MFMA (B-frag = conv C-frag, register-resident) -> tanh/w2 -> block softmax
// -> register-resident weighted pool.  One block (256 thr) per (node, branch).
// ---------------------------------------------------------------------------
__global__ __launch_bounds__(256)
void branch_kernel(const float* __restrict__ x,
                   BranchParams bp0, BranchParams bp1, BranchParams bp2,
                   float* __restrict__ xf)
{
    __shared__ __align__(16) float xs_f[1056];
    __shared__ __align__(8)  _Float16 xsc[4][1048];   // 4 shift-staggered fp16 copies
    __shared__ __align__(8)  _Float16 cws16[256];     // conv A-frag [ch][16 taps], BN-folded
    __shared__ float s_arr[1024];                     // scores, then softmax weights
    __shared__ __align__(16) float shiftc[16];
    __shared__ float scl[16];
    __shared__ float redm[4], reds[4];
    __shared__ __align__(16) float fredw[4][16];

    const BranchParams bp = (blockIdx.y==0)? bp0 : (blockIdx.y==1)? bp1 : bp2;
    const int tid = threadIdx.x;
    const int node = blockIdx.x;
    const int K = bp.K;
    const float* xrow = x + (size_t)node*T_LEN;

    for (int j=tid;j<1056;j+=256){
        int q = j-8;
        xs_f[j] = (q>=0 && q<T_LEN)? xrow[q] : 0.f;
    }
    if (tid<16){
        float s = bp.bn_g[tid]*rsqrtf(bp.bn_v[tid]+BN_EPS);
        scl[tid]=s;
        shiftc[tid] = (bp.conv_b[tid]-bp.bn_m[tid])*s + bp.bn_b[tid];
    }
    __syncthreads();
    for (int j=tid;j<1048;j+=256){
        xsc[0][j]=(_Float16)xs_f[j];
        xsc[1][j]=(_Float16)xs_f[j+1];
        xsc[2][j]=(_Float16)xs_f[j+2];
        xsc[3][j]=(_Float16)xs_f[j+3];
    }
    {
        int ch=tid>>4, tap=tid&15;
        cws16[tid] = (tap<K)? (_Float16)(bp.conv_w[ch*K+tap]*scl[ch]) : (_Float16)0.f;
    }
    __syncthreads();

    const int lane = tid&63, wave = tid>>6;
    const int col  = lane&15;            // B col / C col (position in tile)
    const int kg   = (lane>>4)<<2;       // k-group base / C row base

    // conv A-frag + bias C-op
    const half4_t  acw = *(const half4_t*)&cws16[col*16+kg];
    const float4_t csh = *(const float4_t*)&shiftc[kg];

    // einsum A-frags (w1 rows 0-15 and 16-31), bias C-ops, w2
    float4_t wr0 = *(const float4_t*)&bp.aw1[(size_t)col*TCH + kg];
    float4_t wr1 = *(const float4_t*)&bp.aw1[(size_t)(col+16)*TCH + kg];
    half4_t a0,a1;
    #pragma unroll
    for (int r=0;r<4;r++){ a0[r]=(_Float16)wr0[r]; a1[r]=(_Float16)wr1[r]; }
    const float4_t c0  = *(const float4_t*)&bp.ab1[kg];
    const float4_t c1  = *(const float4_t*)&bp.ab1[16+kg];
    const float4_t w20 = *(const float4_t*)&bp.aw2[kg];
    const float4_t w21 = *(const float4_t*)&bp.aw2[16+kg];
    const float b2v = bp.ab2[0];
    const float w2sum8 = w20[0]+w20[1]+w20[2]+w20[3]+w21[0]+w21[1]+w21[2]+w21[3];
    const float TWO_LOG2E = 2.8853900817779268f;

    // im2col window base: element index a = 8 + pos0 + col + kg - K/2;
    // pos0 steps by 16 per tile => (a & 3) constant across tiles.
    const int abase = 8 + wave*256 + col + kg - K/2;
    const int sh = abase & 3;
    const _Float16* xw_base = &xsc[sh][abase - sh];

    half4_t oreg[16];
    #pragma unroll
    for (int i=0;i<16;i++){
        half4_t xw = *(const half4_t*)(xw_base + i*16);
        float4_t d = __builtin_amdgcn_mfma_f32_16x16x16f16(acw, xw, csh, 0,0,0);
        half4_t ob;
        #pragma unroll
        for (int r=0;r<4;r++) ob[r] = (_Float16)fast_gelu(d[r]);
        oreg[i] = ob;
        float4_t h0 = __builtin_amdgcn_mfma_f32_16x16x16f16(a0, ob, c0, 0,0,0);
        float4_t h1 = __builtin_amdgcn_mfma_f32_16x16x16f16(a1, ob, c1, 0,0,0);
        float accr = 0.f;
        #pragma unroll
        for (int r=0;r<4;r++){
            accr += w20[r]*fast_rcp(__builtin_amdgcn_exp2f(h0[r]*TWO_LOG2E)+1.0f);
            accr += w21[r]*fast_rcp(__builtin_amdgcn_exp2f(h1[r]*TWO_LOG2E)+1.0f);
        }
        float part = w2sum8 - 2.0f*accr;
        part += __shfl_xor(part,16);
        part += __shfl_xor(part,32);
        const int pos0 = wave*256 + i*16;
        if (lane<16) s_arr[pos0+lane] = (pos0+lane < T_LEN)? (part + b2v) : -INFINITY;
    }
    __syncthreads();

    // block softmax over 1000 positions
    float sv[4];
    #pragma unroll
    for (int ii=0;ii<4;ii++) sv[ii]=s_arr[tid+ii*256];
    float m = fmaxf(fmaxf(sv[0],sv[1]),fmaxf(sv[2],sv[3]));
    #pragma unroll
    for (int off=32;off;off>>=1) m = fmaxf(m, __shfl_xor(m,off));
    if (lane==0) redm[wave]=m;
    __syncthreads();
    const float bm = fmaxf(fmaxf(redm[0],redm[1]),fmaxf(redm[2],redm[3]));
    float e[4]; float ls=0.f;
    #pragma unroll
    for (int ii=0;ii<4;ii++){ e[ii]=__expf(sv[ii]-bm); ls+=e[ii]; }
    #pragma unroll
    for (int off=32;off;off>>=1) ls += __shfl_xor(ls,off);
    if (lane==0) reds[wave]=ls;
    __syncthreads();
    const float invS = fast_rcp(reds[0]+reds[1]+reds[2]+reds[3]);
    #pragma unroll
    for (int ii=0;ii<4;ii++) s_arr[tid+ii*256]=e[ii];
    __syncthreads();

    // weighted pool from register-resident o
    float4_t acc = {0.f,0.f,0.f,0.f};
    #pragma unroll
    for (int i=0;i<16;i++){
        float ev = s_arr[wave*256 + i*16 + col];
        half4_t ob = oreg[i];
        #pragma unroll
        for (int r=0;r<4;r++) acc[r] += (float)ob[r]*ev;
    }
    #pragma unroll
    for (int off=1;off<16;off<<=1){
        #pragma unroll
        for (int r=0;r<4;r++) acc[r] += __shfl_xor(acc[r], off);
    }
    if (col==0) *(float4_t*)&fredw[wave][kg] = acc;
    __syncthreads();
    if (tid<16){
        float v = (fredw[0][tid]+fredw[1][tid]+fredw[2][tid]+fredw[3][tid])*invS;
        xf[(size_t)node*F3D + bp.col0 + tid] = v;
    }
}

// ---------------------------------------------------------------------------
// SE block
// ---------------------------------------------------------------------------
__global__ __launch_bounds__(256)
void colsum_kernel(const float* __restrict__ xf, float* __restrict__ colmean){
    int col = blockIdx.x;
    int tid = threadIdx.x;
    float s=0.f;
    for (int i=tid;i<N_NODES;i+=256) s += xf[(size_t)i*F3D+col];
    #pragma unroll
    for (int off=32;off;off>>=1) s += __shfl_xor(s,off);
    __shared__ float red[4];
    if ((tid&63)==0) red[tid>>6]=s;
    __syncthreads();
    if (tid==0) colmean[col] = (red[0]+red[1]+red[2]+red[3])*(1.0f/(float)N_NODES);
}

__global__ __launch_bounds__(64)
void gate_kernel(const float* __restrict__ colmean,
                 const float* __restrict__ se_w1, const float* __restrict__ se_b1,
                 const float* __restrict__ se_w2, const float* __restrict__ se_b2,
                 float* __restrict__ gate){
    __shared__ float sq[F3D];
    __shared__ float g1[12];
    int tid=threadIdx.x;
    if (tid<F3D) sq[tid]=colmean[tid];
    __syncthreads();
    if (tid<12){
        float v=se_b1[tid];
        for (int j=0;j<F3D;j++) v += se_w1[tid*F3D+j]*sq[j];
        g1[tid]=gelu_exact(v);
    }
    __syncthreads();
    if (tid<F3D){
        float v=se_b2[tid];
        for (int m2=0;m2<12;m2++) v += se_w2[tid*12+m2]*g1[m2];
        gate[tid] = fast_rcp(1.0f+__expf(-v));
    }
}

// ---------------------------------------------------------------------------
// CSR build
// ---------------------------------------------------------------------------
__device__ __forceinline__ void edge_decode(const int* __restrict__ ei, int epg,
                                            int e, int be, int& src, int& dst){
    if (e < be){ int b=e/epg, j=e-b*epg; src=ei[j]+b*NPG; dst=ei[epg+j]+b*NPG; }
    else { src=dst=e-be; }
}

__global__ __launch_bounds__(256)
void edge_count(const int* __restrict__ ei, int epg, int* __restrict__ deg){
    int e = blockIdx.x*256+threadIdx.x;
    int be = NGRAPH*epg, total = be + N_NODES;
    if (e>=total) return;
    int s,d; edge_decode(ei,epg,e,be,s,d);
    atomicAdd(&deg[d],1);
}

__global__ __launch_bounds__(1024)
void scan_kernel(const int* __restrict__ deg, int* __restrict__ rowstart,
                 int* __restrict__ cursor){
    __shared__ int part[1024];
    int tid=threadIdx.x;
    int v0=deg[tid*4],v1=deg[tid*4+1],v2=deg[tid*4+2],v3=deg[tid*4+3];
    part[tid]=v0+v1+v2+v3;
    __syncthreads();
    for (int off=1;off<1024;off<<=1){
        int t=(tid>=off)?part[tid-off]:0;
        __syncthreads();
        part[tid]+=t;
        __syncthreads();
    }
    int base=(tid>0)?part[tid-1]:0;
    int r0=base, r1=r0+v0, r2=r1+v1, r3=r2+v2;
    rowstart[tid*4]=r0; rowstart[tid*4+1]=r1; rowstart[tid*4+2]=r2; rowstart[tid*4+3]=r3;
    cursor[tid*4]=r0;   cursor[tid*4+1]=r1;   cursor[tid*4+2]=r2;   cursor[tid*4+3]=r3;
    if (tid==1023) rowstart[4096]=part[1023];
}

__global__ __launch_bounds__(256)
void edge_fill(const int* __restrict__ ei, int epg, int* __restrict__ cursor,
               int* __restrict__ cols){
    int e = blockIdx.x*256+threadIdx.x;
    int be = NGRAPH*epg, total = be + N_NODES;
    if (e>=total) return;
    int s,d; edge_decode(ei,epg,e,be,s,d);
    int pos = atomicAdd(&cursor[d],1);
    cols[pos]=s;
}

// ---------------------------------------------------------------------------
// GAT: node transform h = x @ W.T plus attention logits
// ---------------------------------------------------------------------------
template<int INF, bool GATED>
__global__ __launch_bounds__(128)
void gat_h_kernel(const float* __restrict__ xin_g, const float* __restrict__ gate,
                  const float* __restrict__ W,
                  const float* __restrict__ a_src, const float* __restrict__ a_dst,
                  float* __restrict__ hbuf, float* __restrict__ als, float* __restrict__ ald){
    __shared__ float xin[INF];
    __shared__ float hs[128];
    int node=blockIdx.x, tid=threadIdx.x;
    if (tid<INF){
        float v = xin_g[(size_t)node*INF+tid];
        if (GATED) v *= gate[tid];
        xin[tid]=v;
    }
    __syncthreads();
    float acc=0.f;
    const float* wr = W + (size_t)tid*INF;
    #pragma unroll
    for (int j=0;j<INF;j++) acc += wr[j]*xin[j];
    hs[tid]=acc;
    hbuf[(size_t)node*128+tid]=acc;
    __syncthreads();
    if (tid<8){
        int head=tid&3;
        const float* av = (tid<4)? a_src : a_dst;
        float s=0.f;
        for (int c=0;c<GCD;c++) s += hs[head*GCD+c]*av[head*GCD+c];
        if (tid<4) als[(size_t)node*4+head]=s;
        else       ald[(size_t)node*4+head]=s;
    }
}

// ---------------------------------------------------------------------------
// CSR gather + softmax + head-mean + BN (+skip) + GELU, fused. 8 nodes/block.
// ---------------------------------------------------------------------------
__global__ __launch_bounds__(256)
void gat_gather1(const int* __restrict__ rowstart, const int* __restrict__ cols,
                 const float* __restrict__ als, const float* __restrict__ ald,
                 const float* __restrict__ hbuf,
                 const float* __restrict__ bias,
                 const float* __restrict__ bn_g, const float* __restrict__ bn_b,
                 const float* __restrict__ bn_m, const float* __restrict__ bn_v,
                 const float* __restrict__ xf, const float* __restrict__ gate,
                 const float* __restrict__ skip_w, const float* __restrict__ skip_b,
                 float* __restrict__ h1){
    const int node = blockIdx.x*8 + (threadIdx.x>>5);
    const int c = threadIdx.x&31;
    const float4 ad = ((const float4*)ald)[node];
    float n0=0,n1=0,n2=0,n3=0,d0=0,d1=0,d2=0,d3=0;
    const int s0=rowstart[node], s1=rowstart[node+1];
    for (int e=s0;e<s1;e++){
        const int src=cols[e];
        const float4 as=((const float4*)als)[src];
        float e0=as.x+ad.x; e0=e0>0.f?e0:0.2f*e0; float w0=__expf(e0);
        float e1=as.y+ad.y; e1=e1>0.f?e1:0.2f*e1; float w1=__expf(e1);
        float e2=as.z+ad.z; e2=e2>0.f?e2:0.2f*e2; float w2=__expf(e2);
        float e3=as.w+ad.w; e3=e3>0.f?e3:0.2f*e3; float w3=__expf(e3);
        const float* hr=&hbuf[(size_t)src*128];
        n0+=w0*hr[c]; n1+=w1*hr[32+c]; n2+=w2*hr[64+c]; n3+=w3*hr[96+c];
        d0+=w0; d1+=w1; d2+=w2; d3+=w3;
    }
    float acc = 0.25f*(n0*fast_rcp(d0)+n1*fast_rcp(d1)+n2*fast_rcp(d2)+n3*fast_rcp(d3)) + bias[c];
    acc = (acc-bn_m[c])*rsqrtf(bn_v[c]+BN_EPS)*bn_g[c]+bn_b[c];
    float sk = skip_b[c];
    const float* xr=&xf[(size_t)node*F3D];
    #pragma unroll
    for (int j=0;j<F3D;j++) sk += xr[j]*gate[j]*skip_w[c*F3D+j];
    h1[(size_t)node*GCD+c]=gelu_exact(acc+sk);
}

__global__ __launch_bounds__(256)
void gat_gather2(const int* __restrict__ rowstart, const int* __restrict__ cols,
                 const float* __restrict__ als, const float* __restrict__ ald,
                 const float* __restrict__ hbuf,
                 const float* __restrict__ bias,
                 const float* __restrict__ bn_g, const float* __restrict__ bn_b,
                 const float* __restrict__ bn_m, const float* __restrict__ bn_v,
                 const float* __restrict__ h1, float* __restrict__ h2){
    const int node = blockIdx.x*8 + (threadIdx.x>>5);
    const int c = threadIdx.x&31;
    const float4 ad = ((const float4*)ald)[node];
    float n0=0,n1=0,n2=0,n3=0,d0=0,d1=0,d2=0,d3=0;
    const int s0=rowstart[node], s1=rowstart[node+1];
    for (int e=s0;e<s1;e++){
        const int src=cols[e];
        const float4 as=((const float4*)als)[src];
        float e0=as.x+ad.x; e0=e0>0.f?e0:0.2f*e0; float w0=__expf(e0);
        float e1=as.y+ad.y; e1=e1>0.f?e1:0.2f*e1; float w1=__expf(e1);
        float e2=as.z+ad.z; e2=e2>0.f?e2:0.2f*e2; float w2=__expf(e2);
        float e3=as.w+ad.w; e3=e3>0.f?e3:0.2f*e3; float w3=__expf(e3);
        const float* hr=&hbuf[(size_t)src*128];
        n0+=w0*hr[c]; n1+=w1*hr[32+c]; n2+=w2*hr[64+c]; n3+=w3*hr[96+c];
        d0+=w0; d1+=w1; d2+=w2; d3+=w3;
    }
    float acc = 0.25f*(n0*fast_rcp(d0)+n1*fast_rcp(d1)+n2*fast_rcp(d2)+n3*fast_rcp(d3)) + bias[c];
    acc = (acc-bn_m[c])*rsqrtf(bn_v[c]+BN_EPS)*bn_g[c]+bn_b[c];
    float v = acc + h1[(size_t)node*GCD+c];
    h2[(size_t)node*GCD+c]=gelu_exact(v);
}

__global__ __launch_bounds__(64)
void pool_fc_kernel(const float* __restrict__ h2, const float* __restrict__ fc_w,
                    const float* __restrict__ fc_b, float* __restrict__ out){
    int g = blockIdx.x;
    int tid = threadIdx.x;
    __shared__ float part[2][GCD];
    __shared__ float pool[GCD];
    int c = tid&31, hf = tid>>5;
    float acc=0.f;
    for (int i=hf*32;i<hf*32+32;i++) acc += h2[((size_t)(g*NPG+i))*GCD+c];
    part[hf][c]=acc;
    __syncthreads();
    if (tid<GCD) pool[tid]=(part[0][tid]+part[1][tid])*(1.0f/(float)NPG);
    __syncthreads();
    if (tid<2){
        float o=fc_b[tid];
        for (int cc=0;cc<GCD;cc++) o += pool[cc]*fc_w[tid*GCD+cc];
        out[g*2+tid]=o;
    }
}

// ---------------------------------------------------------------------------
extern "C" void kernel_launch(void* const* d_in, const int* in_sizes, int n_in,
                              void* d_out, int out_size, void* d_ws, size_t ws_size,
                              hipStream_t stream){
    const float* x = (const float*)d_in[0];
    const int* ei = (const int*)d_in[1];
    const int epg = in_sizes[1]/2;

    float* ws = (float*)d_ws;
    float* xf      = ws;                                   // [4096,48]
    float* colmean = xf + (size_t)N_NODES*F3D;             // 64
    float* gate    = colmean + 64;                         // 64
    float* hbuf    = gate + 64;                            // [4096,128]
    float* als     = hbuf + (size_t)N_NODES*128;           // [4096,4]
    float* ald     = als + (size_t)N_NODES*4;              // [4096,4]
    float* h1      = ald + (size_t)N_NODES*4;              // [4096,32]
    float* h2      = h1 + (size_t)N_NODES*GCD;             // [4096,32]
    int*   deg      = (int*)(h2 + (size_t)N_NODES*GCD);    // [4096]
    int*   rowstart = deg + N_NODES;                       // [4097]
    int*   cursor   = rowstart + N_NODES + 1;              // [4096]
    int*   cols     = cursor + N_NODES;                    // [~41K]

    auto P = [&](int i){ return (const float*)d_in[i]; };

    const int etot = NGRAPH*epg + N_NODES;
    hipMemsetAsync(deg, 0, (size_t)N_NODES*sizeof(int), stream);
    edge_count<<<(etot+255)/256,256,0,stream>>>(ei,epg,deg);
    scan_kernel<<<1,1024,0,stream>>>(deg,rowstart,cursor);
    edge_fill<<<(etot+255)/256,256,0,stream>>>(ei,epg,cursor,cols);

    BranchParams bps[3];
    const int Ks[3] = {3,5,7};
    for (int b=0;b<3;b++){
        int base = 2 + b*10;
        bps[b].conv_w = P(base+0); bps[b].conv_b = P(base+1);
        bps[b].bn_g = P(base+2);   bps[b].bn_b = P(base+3);
        bps[b].bn_m = P(base+4);   bps[b].bn_v = P(base+5);
        bps[b].aw1 = P(base+6);    bps[b].ab1 = P(base+7);
        bps[b].aw2 = P(base+8);    bps[b].ab2 = P(base+9);
        bps[b].K = Ks[b]; bps[b].col0 = b*TCH;
    }
    branch_kernel<<<dim3(N_NODES,3),256,0,stream>>>(x, bps[0], bps[1], bps[2], xf);

    colsum_kernel<<<F3D,256,0,stream>>>(xf,colmean);
    gate_kernel<<<1,64,0,stream>>>(colmean,P(32),P(33),P(34),P(35),gate);

    gat_h_kernel<F3D,true><<<N_NODES,128,0,stream>>>(xf,gate,P(36),P(37),P(38),hbuf,als,ald);
    gat_gather1<<<N_NODES/8,256,0,stream>>>(rowstart,cols,als,ald,hbuf,
                                            P(39),P(40),P(41),P(42),P(43),
                                            xf,gate,P(44),P(45),h1);

    gat_h_kernel<GCD,false><<<N_NODES,128,0,stream>>>(h1,nullptr,P(46),P(47),P(48),hbuf,als,ald);
    gat_gather2<<<N_NODES/8,256,0,stream>>>(rowstart,cols,als,ald,hbuf,
                                            P(49),P(50),P(51),P(52),P(53),
                                            h1,h2);

    pool_fc_kernel<<<NGRAPH,64,0,stream>>>(h2,P(54),P(55),(float*)d_out);
}